// Round 9
// baseline (1191.419 us; speedup 1.0000x reference)
//
#include <hip/hip_runtime.h>

// B=4096, T=512, IN=32, H=[64,64,128], OUT=10
// 256 blocks (1/CU) x 256 threads (4 waves = 1 wave/SIMD -> 512-reg unified budget).
// ALL weights register-resident per wave (304 regs): W0x/W0h (48) in arch VGPRs;
// W1a/W1h/W2a/W2h (256) PINNED INTO AGPRs via empty inline-asm "+a" constraints.
// All MFMAs are BUILTINS (srcA/B are AV-class on gfx950 -> can read AGPRs directly;
// compiler handles all hazards — the R4/R6 asm-MFMA hazard trap is avoided).
// h states double-buffered in LDS (~18KB). x prefetched one step ahead.
// R2 retry with the arch-VGPR overflow moved to AGPRs instead of scratch.

using f32x4  = __attribute__((ext_vector_type(4))) float;
using bf16x8 = __attribute__((ext_vector_type(8))) __bf16;

__device__ __forceinline__ __bf16 f2bf(float f) {
  unsigned u = __builtin_bit_cast(unsigned, f);
  unsigned short s = (unsigned short)((u + 0x7fffu + ((u >> 16) & 1u)) >> 16);
  return __builtin_bit_cast(__bf16, s);
}
__device__ __forceinline__ float bf2f(__bf16 b) {
  unsigned short s = __builtin_bit_cast(unsigned short, b);
  unsigned u = ((unsigned)s) << 16;
  return __builtin_bit_cast(float, u);
}
__device__ __forceinline__ float fsig(float x) {
  return __builtin_amdgcn_rcpf(1.0f + __builtin_amdgcn_exp2f(-1.442695041f * x));
}
__device__ __forceinline__ float ftanh(float x) {
  return 2.0f * __builtin_amdgcn_rcpf(1.0f + __builtin_amdgcn_exp2f(-2.885390082f * x)) - 1.0f;
}

#define MF(A, Bv, C) __builtin_amdgcn_mfma_f32_16x16x32_bf16((A), (Bv), (C), 0, 0, 0)
// Pin a bf16x8 value into AGPRs (4-reg tuple). No instructions emitted -> no hazards.
#define PIN_A(v) asm volatile("" : "+a"(v))

__device__ __forceinline__ bf16x8 ldw8(const float* p) {
  float4 v0 = *(const float4*)p;
  float4 v1 = *(const float4*)(p + 4);
  bf16x8 r;
  r[0] = f2bf(v0.x); r[1] = f2bf(v0.y); r[2] = f2bf(v0.z); r[3] = f2bf(v0.w);
  r[4] = f2bf(v1.x); r[5] = f2bf(v1.y); r[6] = f2bf(v1.z); r[7] = f2bf(v1.w);
  return r;
}

__global__ __launch_bounds__(256, 1)
void lstm_kernel(const float* __restrict__ x,
                 const float* __restrict__ Wih0, const float* __restrict__ Whh0,
                 const float* __restrict__ bih0, const float* __restrict__ bhh0,
                 const float* __restrict__ Wih1, const float* __restrict__ Whh1,
                 const float* __restrict__ bih1, const float* __restrict__ bhh1,
                 const float* __restrict__ Wih2, const float* __restrict__ Whh2,
                 const float* __restrict__ bih2, const float* __restrict__ bhh2,
                 const float* __restrict__ Wfc, const float* __restrict__ bfc,
                 float* __restrict__ out) {
  // double-buffered h states (row stride 72/136 shorts -> benign 2-way bank aliasing)
  __shared__ __align__(16) __bf16 h0s[2][16][72];
  __shared__ __align__(16) __bf16 h1s[2][16][72];
  __shared__ __align__(16) __bf16 h2s[2][16][136];

  const int tid = threadIdx.x;
  const int w   = tid >> 6;   // wave 0..3
  const int l   = tid & 63;
  const int l15 = l & 15;
  const int lg  = l >> 4;     // 0..3
  const int k0  = lg * 8;
  const int r0  = blockIdx.x << 4;

  for (int i = tid; i < 2 * 16 * 72; i += 256) {
    (&h0s[0][0][0])[i] = __bf16(0.f);
    (&h1s[0][0][0])[i] = __bf16(0.f);
  }
  for (int i = tid; i < 2 * 16 * 136; i += 256) (&h2s[0][0][0])[i] = __bf16(0.f);

  // ---- weight slices ----
  bf16x8 W0x[4];        // arch VGPR: Wih0 [gi], tile=4gi+w, K=32
  bf16x8 W0h[4][2];     // arch VGPR: Whh0 [gi][kb]
  bf16x8 W1a[4][2];     // AGPR: Wih1
  bf16x8 W1h[4][2];     // AGPR: Whh1
  bf16x8 W2a[2][4][2];  // AGPR: Wih2, tile=8gi+2w+s
  bf16x8 W2h[2][4][4];  // AGPR: Whh2
#pragma unroll
  for (int gi = 0; gi < 4; ++gi) {
    const int row = 16 * (4 * gi + w) + l15;
    W0x[gi] = ldw8(Wih0 + (size_t)row * 32 + k0);
#pragma unroll
    for (int kb = 0; kb < 2; ++kb) {
      W0h[gi][kb] = ldw8(Whh0 + (size_t)row * 64 + kb * 32 + k0);
      W1a[gi][kb] = ldw8(Wih1 + (size_t)row * 64 + kb * 32 + k0);
      W1h[gi][kb] = ldw8(Whh1 + (size_t)row * 64 + kb * 32 + k0);
    }
  }
#pragma unroll
  for (int s = 0; s < 2; ++s)
#pragma unroll
    for (int gi = 0; gi < 4; ++gi) {
      const int row = 16 * (8 * gi + 2 * w + s) + l15;
#pragma unroll
      for (int kb = 0; kb < 2; ++kb)
        W2a[s][gi][kb] = ldw8(Wih2 + (size_t)row * 64 + kb * 32 + k0);
#pragma unroll
      for (int kk = 0; kk < 4; ++kk)
        W2h[s][gi][kk] = ldw8(Whh2 + (size_t)row * 128 + kk * 32 + k0);
    }

  // ---- pin the overflow weights into AGPRs (64 slots = 256 AGPRs exactly) ----
#pragma unroll
  for (int gi = 0; gi < 4; ++gi)
#pragma unroll
    for (int kb = 0; kb < 2; ++kb) { PIN_A(W1a[gi][kb]); PIN_A(W1h[gi][kb]); }
#pragma unroll
  for (int s = 0; s < 2; ++s)
#pragma unroll
    for (int gi = 0; gi < 4; ++gi) {
#pragma unroll
      for (int kb = 0; kb < 2; ++kb) PIN_A(W2a[s][gi][kb]);
#pragma unroll
      for (int kk = 0; kk < 4; ++kk) PIN_A(W2h[s][gi][kk]);
    }

  float bias0[4], bias1[4], bias2[2][4];
#pragma unroll
  for (int gi = 0; gi < 4; ++gi) {
    const int c01 = 64 * gi + 16 * w + l15;
    bias0[gi] = bih0[c01] + bhh0[c01];
    bias1[gi] = bih1[c01] + bhh1[c01];
  }
#pragma unroll
  for (int s = 0; s < 2; ++s)
#pragma unroll
    for (int gi = 0; gi < 4; ++gi) {
      const int c2 = 128 * gi + 32 * w + 16 * s + l15;
      bias2[s][gi] = bih2[c2] + bhh2[c2];
    }

  float c0v[4] = {0.f, 0.f, 0.f, 0.f};
  float c1v[4] = {0.f, 0.f, 0.f, 0.f};
  float c2v[2][4] = {{0.f, 0.f, 0.f, 0.f}, {0.f, 0.f, 0.f, 0.f}};

  // x prefetch (one step ahead)
  const float* xrow = x + (size_t)(r0 + l15) * 512 * 32 + k0;
  float4 nx0 = *(const float4*)xrow;
  float4 nx1 = *(const float4*)(xrow + 4);

  __syncthreads();

#pragma unroll 1
  for (int t = 0; t < 512; ++t) {
    const int p  = t & 1;
    const int rb = p ^ 1;

    float4 cx0 = nx0, cx1 = nx1;
    {
      const int tn = (t + 1) & 511;  // wraparound dummy load at t=511
      const float* xp = xrow + (size_t)tn * 32;
      nx0 = *(const float4*)xp;
      nx1 = *(const float4*)(xp + 4);
    }

    // ================= layer 0 =================
    bf16x8 ax;
    ax[0] = f2bf(cx0.x); ax[1] = f2bf(cx0.y); ax[2] = f2bf(cx0.z); ax[3] = f2bf(cx0.w);
    ax[4] = f2bf(cx1.x); ax[5] = f2bf(cx1.y); ax[6] = f2bf(cx1.z); ax[7] = f2bf(cx1.w);

    bf16x8 a0 = *(const bf16x8*)&h0s[rb][l15][k0];
    bf16x8 a1 = *(const bf16x8*)&h0s[rb][l15][32 + k0];

    f32x4 acc[4];
#pragma unroll
    for (int gi = 0; gi < 4; ++gi) {
      f32x4 a = {bias0[gi], bias0[gi], bias0[gi], bias0[gi]};
      a = MF(ax, W0x[gi], a);
      a = MF(a0, W0h[gi][0], a);
      a = MF(a1, W0h[gi][1], a);
      acc[gi] = a;
    }
#pragma unroll
    for (int j = 0; j < 4; ++j) {
      float nc = fsig(acc[1][j]) * c0v[j] + fsig(acc[0][j]) * ftanh(acc[2][j]);
      c0v[j] = nc;
      h0s[p][4 * lg + j][16 * w + l15] = f2bf(fsig(acc[3][j]) * ftanh(nc));
    }
    __syncthreads();  // B1: h0(t) visible

    // ================= layer 1 =================
    a0 = *(const bf16x8*)&h0s[p][l15][k0];
    a1 = *(const bf16x8*)&h0s[p][l15][32 + k0];
    bf16x8 b0 = *(const bf16x8*)&h1s[rb][l15][k0];
    bf16x8 b1 = *(const bf16x8*)&h1s[rb][l15][32 + k0];
#pragma unroll
    for (int gi = 0; gi < 4; ++gi) {
      f32x4 a = {bias1[gi], bias1[gi], bias1[gi], bias1[gi]};
      a = MF(a0, W1a[gi][0], a);
      a = MF(a1, W1a[gi][1], a);
      a = MF(b0, W1h[gi][0], a);
      a = MF(b1, W1h[gi][1], a);
      acc[gi] = a;
    }
#pragma unroll
    for (int j = 0; j < 4; ++j) {
      float nc = fsig(acc[1][j]) * c1v[j] + fsig(acc[0][j]) * ftanh(acc[2][j]);
      c1v[j] = nc;
      h1s[p][4 * lg + j][16 * w + l15] = f2bf(fsig(acc[3][j]) * ftanh(nc));
    }
    __syncthreads();  // B2: h1(t) visible

    // ================= layer 2 =================
    a0 = *(const bf16x8*)&h1s[p][l15][k0];
    a1 = *(const bf16x8*)&h1s[p][l15][32 + k0];
    bf16x8 d0 = *(const bf16x8*)&h2s[rb][l15][k0];
    bf16x8 d1 = *(const bf16x8*)&h2s[rb][l15][32 + k0];
    bf16x8 d2 = *(const bf16x8*)&h2s[rb][l15][64 + k0];
    bf16x8 d3 = *(const bf16x8*)&h2s[rb][l15][96 + k0];

    f32x4 acc2[2][4];
#pragma unroll
    for (int s = 0; s < 2; ++s)
#pragma unroll
      for (int gi = 0; gi < 4; ++gi) {
        f32x4 a = {bias2[s][gi], bias2[s][gi], bias2[s][gi], bias2[s][gi]};
        a = MF(a0, W2a[s][gi][0], a);
        a = MF(a1, W2a[s][gi][1], a);
        a = MF(d0, W2h[s][gi][0], a);
        a = MF(d1, W2h[s][gi][1], a);
        a = MF(d2, W2h[s][gi][2], a);
        a = MF(d3, W2h[s][gi][3], a);
        acc2[s][gi] = a;
      }
#pragma unroll
    for (int s = 0; s < 2; ++s)
#pragma unroll
      for (int j = 0; j < 4; ++j) {
        float nc = fsig(acc2[s][1][j]) * c2v[s][j] + fsig(acc2[s][0][j]) * ftanh(acc2[s][2][j]);
        c2v[s][j] = nc;
        h2s[p][4 * lg + j][32 * w + 16 * s + l15] = f2bf(fsig(acc2[s][3][j]) * ftanh(nc));
      }
    __syncthreads();  // B3: h2(t) visible
  }

  // ================= final FC: out = h2(511) @ Wfc^T + bfc (buffer 1) ==========
  if (tid < 160) {
    const int r = tid / 10, o = tid - r * 10;
    float sum = bfc[o];
    for (int u = 0; u < 128; ++u) sum += bf2f(h2s[1][r][u]) * Wfc[o * 128 + u];
    out[(size_t)(r0 + r) * 10 + o] = sum;
  }
}

extern "C" void kernel_launch(void* const* d_in, const int* in_sizes, int n_in,
                              void* d_out, int out_size, void* d_ws, size_t ws_size,
                              hipStream_t stream) {
  const float* x    = (const float*)d_in[0];
  const float* Wih0 = (const float*)d_in[1];
  const float* Whh0 = (const float*)d_in[2];
  const float* bih0 = (const float*)d_in[3];
  const float* bhh0 = (const float*)d_in[4];
  const float* Wih1 = (const float*)d_in[5];
  const float* Whh1 = (const float*)d_in[6];
  const float* bih1 = (const float*)d_in[7];
  const float* bhh1 = (const float*)d_in[8];
  const float* Wih2 = (const float*)d_in[9];
  const float* Whh2 = (const float*)d_in[10];
  const float* bih2 = (const float*)d_in[11];
  const float* bhh2 = (const float*)d_in[12];
  const float* Wfc  = (const float*)d_in[13];
  const float* bfc  = (const float*)d_in[14];

  lstm_kernel<<<256, 256, 0, stream>>>(x, Wih0, Whh0, bih0, bhh0,
                                       Wih1, Whh1, bih1, bhh1,
                                       Wih2, Whh2, bih2, bhh2,
                                       Wfc, bfc, (float*)d_out);
}